// Round 5
// baseline (2529.375 us; speedup 1.0000x reference)
//
#include <hip/hip_runtime.h>
#include <math.h>

#define Bsz 64
#define Pp  196
#define ENC 2048
#define Ee  512
#define Hh  512
#define Vv  10000
#define Tt  20
#define H4  2048

typedef short bf16x8 __attribute__((ext_vector_type(8)));
typedef float f32x4 __attribute__((ext_vector_type(4)));
typedef unsigned short ushort_t;

__device__ __forceinline__ float sigmoidf_(float x) { return 1.0f / (1.0f + expf(-x)); }

__device__ __forceinline__ unsigned short bf16r(float x) {
    union { float f; unsigned int u; } c; c.f = x;
    unsigned int lsb = (c.u >> 16) & 1u;
    return (unsigned short)((c.u + 0x7fffu + lsb) >> 16);
}

// hi/lo split helpers: hi = round-to-nearest bf16 (packed pair), lo = residual
__device__ __forceinline__ unsigned int hi2(float a, float b, float& la, float& lb) {
    unsigned int ua = __float_as_uint(a), ub = __float_as_uint(b);
    unsigned int ha = (ua + 0x8000u) & 0xFFFF0000u;
    unsigned int hb = (ub + 0x8000u) & 0xFFFF0000u;
    la = a - __uint_as_float(ha);
    lb = b - __uint_as_float(hb);
    return (ha >> 16) | hb;
}
__device__ __forceinline__ unsigned int lo2(float la, float lb) {
    unsigned int ua = __float_as_uint(la), ub = __float_as_uint(lb);
    return ((ua + 0x8000u) >> 16) | ((ub + 0x8000u) & 0xFFFF0000u);
}

// ---------------- v_enc[e] = sum_a W_full[a] * W_enc[a][e] ----------------
__global__ __launch_bounds__(256) void k_venc(const float* __restrict__ W_full,
                                              const float* __restrict__ W_enc,
                                              float* __restrict__ v_enc) {
    int lane = threadIdx.x & 63, ag = threadIdx.x >> 6;
    int e = blockIdx.x * 64 + lane;
    float s = 0.f;
    #pragma unroll 8
    for (int a = ag * 128; a < ag * 128 + 128; ++a)
        s += W_full[a] * W_enc[(size_t)a * ENC + e];
    __shared__ float red[4][64];
    red[ag][lane] = s;
    __syncthreads();
    if (threadIdx.x < 64)
        v_enc[e] = red[0][lane] + red[1][lane] + red[2][lane] + red[3][lane];
}

// ---------------- scores ----------------
__global__ __launch_bounds__(256) void k_scores(const float* __restrict__ img,
                                                const float* __restrict__ v_enc,
                                                float* __restrict__ sc) {
    int b = blockIdx.y;
    int wave = threadIdx.x >> 6, lane = threadIdx.x & 63;
    int p = blockIdx.x * 4 + wave;
    __shared__ float4 sv[ENC / 4];
    const float4* ve4 = (const float4*)v_enc;
    sv[threadIdx.x] = ve4[threadIdx.x];
    sv[threadIdx.x + 256] = ve4[threadIdx.x + 256];
    __syncthreads();
    const float4* row = (const float4*)(img + ((size_t)b * Pp + p) * ENC);
    float s = 0.f;
    #pragma unroll
    for (int it = 0; it < 8; ++it) {
        int idx = it * 64 + lane;
        float4 v = row[idx];
        float4 w = sv[idx];
        s += v.x * w.x + v.y * w.y + v.z * w.z + v.w * w.w;
    }
    #pragma unroll
    for (int off = 32; off > 0; off >>= 1) s += __shfl_down(s, off);
    if (lane == 0) sc[b * Pp + p] = s;
}

// ---------------- softmax ----------------
__global__ __launch_bounds__(256) void k_softmax(const float* __restrict__ sc,
                                                 float* __restrict__ alpha,
                                                 float* __restrict__ alphas_out) {
    int b = blockIdx.x, tid = threadIdx.x;
    __shared__ float red[256];
    __shared__ float sa[Pp];
    float v = (tid < Pp) ? sc[b * Pp + tid] : -INFINITY;
    red[tid] = v; __syncthreads();
    for (int off = 128; off > 0; off >>= 1) {
        if (tid < off) red[tid] = fmaxf(red[tid], red[tid + off]);
        __syncthreads();
    }
    float mx = red[0]; __syncthreads();
    float ex = (tid < Pp) ? expf(v - mx) : 0.f;
    red[tid] = ex; __syncthreads();
    for (int off = 128; off > 0; off >>= 1) {
        if (tid < off) red[tid] += red[tid + off];
        __syncthreads();
    }
    float inv = 1.f / red[0];
    if (tid < Pp) { sa[tid] = ex * inv; alpha[b * Pp + tid] = ex * inv; }
    __syncthreads();
    for (int i = tid; i < Tt * Pp; i += 256)
        alphas_out[(size_t)b * Tt * Pp + i] = sa[i % Pp];
}

// ---------------- context + avg ----------------
__global__ __launch_bounds__(256) void k_ctx(const float* __restrict__ img,
                                             const float* __restrict__ alpha,
                                             float* __restrict__ context,
                                             float* __restrict__ avg) {
    int b = blockIdx.y;
    int e2 = blockIdx.x * 256 + threadIdx.x;
    __shared__ float sa[Pp];
    if (threadIdx.x < Pp) sa[threadIdx.x] = alpha[b * Pp + threadIdx.x];
    __syncthreads();
    const float2* ib2 = (const float2*)(img + (size_t)b * Pp * ENC);
    float cx = 0.f, cy = 0.f, ax = 0.f, ay = 0.f;
    for (int p = 0; p < Pp; p += 4) {
        #pragma unroll
        for (int q = 0; q < 4; ++q) {
            float ap = sa[p + q];
            float2 v = ib2[(size_t)(p + q) * (ENC / 2) + e2];
            cx += ap * v.x; cy += ap * v.y;
            ax += v.x;      ay += v.y;
        }
    }
    float2* c2 = (float2*)(context + (size_t)b * ENC);
    float2* a2 = (float2*)(avg + (size_t)b * ENC);
    c2[e2] = make_float2(cx, cy);
    a2[e2] = make_float2(ax * (1.f / 196.f), ay * (1.f / 196.f));
}

// ---------------- init GEMM: h0|c0 = avg @ [Winit_h | Winit_c]^T + bias (fp32) --------
__global__ __launch_bounds__(256) void gemm_init(
    const float* __restrict__ A,
    const float* __restrict__ B0, const float* __restrict__ B1,
    float* __restrict__ h0, float* __restrict__ cbuf,
    const float* __restrict__ bias0, const float* __restrict__ bias1) {
    const int tid = threadIdx.x;
    const int tx = tid & 15, ty = tid >> 4;
    const int n0 = blockIdx.x * 16;

    const float* Brow = (n0 < 512) ? B0 + (size_t)n0 * ENC : B1 + (size_t)(n0 - 512) * ENC;

    __shared__ float As[64][68];
    __shared__ float Bs[64][20];

    float4 pa[4], pb;
    const int sm[4] = { tid >> 4, (256 + tid) >> 4, (512 + tid) >> 4, (768 + tid) >> 4 };
    const int scc = tid & 15;
    const int bn = tid >> 4, bc = tid & 15;

    auto load_chunk = [&](int c) {
        int k0 = c * 64;
        #pragma unroll
        for (int i = 0; i < 4; ++i)
            pa[i] = *(const float4*)(A + (size_t)sm[i] * ENC + k0 + 4 * scc);
        pb = *(const float4*)(Brow + (size_t)bn * ENC + k0 + 4 * bc);
    };

    float acc[4] = {};
    load_chunk(0);
    for (int c = 0; c < 32; ++c) {
        __syncthreads();
        #pragma unroll
        for (int i = 0; i < 4; ++i) {
            As[4 * scc + 0][sm[i]] = pa[i].x;
            As[4 * scc + 1][sm[i]] = pa[i].y;
            As[4 * scc + 2][sm[i]] = pa[i].z;
            As[4 * scc + 3][sm[i]] = pa[i].w;
        }
        Bs[4 * bc + 0][bn] = pb.x;
        Bs[4 * bc + 1][bn] = pb.y;
        Bs[4 * bc + 2][bn] = pb.z;
        Bs[4 * bc + 3][bn] = pb.w;
        __syncthreads();
        if (c + 1 < 32) load_chunk(c + 1);
        #pragma unroll 8
        for (int kk = 0; kk < 64; ++kk) {
            float4 a = *(const float4*)&As[kk][ty * 4];
            float bb = Bs[kk][tx];
            acc[0] += a.x * bb; acc[1] += a.y * bb;
            acc[2] += a.z * bb; acc[3] += a.w * bb;
        }
    }

    int gn = n0 + tx;
    #pragma unroll
    for (int i = 0; i < 4; ++i) {
        int m = ty * 4 + i;
        if (gn < 512) h0[(size_t)m * 512 + gn]           = acc[i] + bias0[gn];
        else          cbuf[(size_t)m * 512 + (gn - 512)] = acc[i] + bias1[gn - 512];
    }
}

// ---------------- emb GEMM, fused gather, PERMUTED output columns (G' = j*4+g) --------
__global__ __launch_bounds__(256) void gemm_emb(const int* __restrict__ captions,
                                                const float* __restrict__ emb,
                                                const float* __restrict__ Bm,
                                                float* __restrict__ C,
                                                const float* __restrict__ bias,
                                                const float* __restrict__ bias2) {
    const int tid = threadIdx.x;
    const int tx = tid & 15, ty = tid >> 4;
    const int m0 = blockIdx.y * 128, n0 = blockIdx.x * 64;

    __shared__ float As[32][132];
    __shared__ float Bs[32][68];

    float4 pa[4], pb[2];
    const int am[4] = { tid >> 3, (256 + tid) >> 3, (512 + tid) >> 3, (768 + tid) >> 3 };
    const int ac = tid & 7;
    const int bnr[2] = { tid >> 3, (256 + tid) >> 3 };
    const int bc = tid & 7;

    const float* arow[4];
    #pragma unroll
    for (int i = 0; i < 4; ++i) {
        int r = m0 + am[i];
        arow[i] = emb + (size_t)captions[(r & 63) * Tt + (r >> 6)] * Ee;
    }
    const float* brow[2];
    #pragma unroll
    for (int i = 0; i < 2; ++i) {
        int n = n0 + bnr[i];
        brow[i] = Bm + (size_t)((n & 3) * 512 + (n >> 2)) * 2560;
    }

    const int nchunk = Ee / 32;
    auto load_chunk = [&](int c) {
        int k0 = c * 32;
        #pragma unroll
        for (int i = 0; i < 4; ++i)
            pa[i] = *(const float4*)(arow[i] + k0 + 4 * ac);
        #pragma unroll
        for (int i = 0; i < 2; ++i)
            pb[i] = *(const float4*)(brow[i] + k0 + 4 * bc);
    };

    float acc[8][4] = {};
    load_chunk(0);
    for (int c = 0; c < nchunk; ++c) {
        __syncthreads();
        #pragma unroll
        for (int i = 0; i < 4; ++i) {
            As[4 * ac + 0][am[i]] = pa[i].x;
            As[4 * ac + 1][am[i]] = pa[i].y;
            As[4 * ac + 2][am[i]] = pa[i].z;
            As[4 * ac + 3][am[i]] = pa[i].w;
        }
        #pragma unroll
        for (int i = 0; i < 2; ++i) {
            Bs[4 * bc + 0][bnr[i]] = pb[i].x;
            Bs[4 * bc + 1][bnr[i]] = pb[i].y;
            Bs[4 * bc + 2][bnr[i]] = pb[i].z;
            Bs[4 * bc + 3][bnr[i]] = pb[i].w;
        }
        __syncthreads();
        if (c + 1 < nchunk) load_chunk(c + 1);
        #pragma unroll 4
        for (int kk = 0; kk < 32; ++kk) {
            float4 a0 = *(const float4*)&As[kk][ty * 8];
            float4 a1 = *(const float4*)&As[kk][ty * 8 + 4];
            float4 b0 = *(const float4*)&Bs[kk][tx * 4];
            float av[8] = { a0.x, a0.y, a0.z, a0.w, a1.x, a1.y, a1.z, a1.w };
            float bv[4] = { b0.x, b0.y, b0.z, b0.w };
            #pragma unroll
            for (int i = 0; i < 8; ++i)
                #pragma unroll
                for (int j = 0; j < 4; ++j)
                    acc[i][j] += av[i] * bv[j];
        }
    }

    #pragma unroll
    for (int i = 0; i < 8; ++i) {
        int m = m0 + ty * 8 + i;
        #pragma unroll
        for (int j = 0; j < 4; ++j) {
            int gn = n0 + tx * 4 + j;
            int G = (gn & 3) * 512 + (gn >> 2);
            C[(size_t)m * H4 + gn] = acc[i][j] + bias[G] + bias2[G];
        }
    }
}

// ---------------- recurrent step: hi/lo-split bf16 MFMA (3-product fp32 emulation) ----
// MODE 0: preact[64][4096] = h @ [W_beta | W_hh(perm)]^T; n<2048 -> gc (fp32,
//         sigmoid*ctx fused); n>=2048 -> P0f[b][G'] (fp32). grid 64.
// MODE 1: gates = gc @ W_ih[perm(G')][512:]^T + emb_t + P0f; fused LSTM ->
//         cbuf, hbuf (fp32), Hbf[(b*20+t)] (bf16). grid 32.
// LDS: per iter stage 64-k chunk, 4 planes (A/B x hi/lo), k-permuted so each
// MFMA fragment is one ds_read_b128.
template<int MODE>
__global__ __launch_bounds__(256) void k_step(
    const float* __restrict__ Asrc, const float* __restrict__ W0,
    const float* __restrict__ W1,
    const float* __restrict__ b_beta, const float* __restrict__ context,
    const float* __restrict__ emb_t, float* __restrict__ P0f,
    float* __restrict__ gc_out, float* __restrict__ cbuf,
    float* __restrict__ hbuf, ushort_t* __restrict__ Hbf, int t) {

    const int tid = threadIdx.x;
    const int n0 = blockIdx.x * 64;
    const int NIT = MODE ? 32 : 8;            // K = NIT*64

    __shared__ __align__(16) unsigned char shraw[40960];
    ushort_t* sAh = (ushort_t*)shraw;          // [2 kc][64][40]
    ushort_t* sAl = sAh + 5120;
    ushort_t* sBh = sAl + 5120;
    ushort_t* sBl = sBh + 5120;

    // staging role: srow = LDS row, q -> {matrix, k-chunk}
    const int srow = tid >> 2, q = tid & 3;
    const int matsel = q >> 1, kc = q & 1;

    const float* base;
    if (matsel == 0) {
        base = Asrc + (size_t)srow * (MODE ? 2048 : 512);
    } else {
        int n = n0 + srow;
        if (MODE == 0) {
            if (n < 2048) base = W0 + (size_t)n * 512;
            else {
                int g = n - 2048;
                base = W1 + (size_t)((g & 3) * 512 + (g >> 2)) * 512;
            }
        } else {
            base = W0 + (size_t)((n & 3) * 512 + (n >> 2)) * 2560 + 512;
        }
    }
    ushort_t* dsth = (matsel ? sBh : sAh) + kc * 2560 + srow * 40;
    ushort_t* dstl = (matsel ? sBl : sAl) + kc * 2560 + srow * 40;

    float4 f[8];
    auto load = [&](int it) {
        const float* p = base + it * 64 + kc * 32;
        #pragma unroll
        for (int i = 0; i < 8; ++i) f[i] = *(const float4*)(p + i * 4);
    };
    auto stage = [&]() {
        #pragma unroll
        for (int i = 0; i < 4; ++i) {
            float4 a = f[i], b2 = f[i + 4];       // k[4i..4i+3], k[16+4i..16+4i+3]
            float l0,l1,l2,l3,l4,l5,l6,l7;
            uint4 ph, pl;
            ph.x = hi2(a.x,  a.y,  l0, l1);
            ph.y = hi2(a.z,  a.w,  l2, l3);
            ph.z = hi2(b2.x, b2.y, l4, l5);
            ph.w = hi2(b2.z, b2.w, l6, l7);
            pl.x = lo2(l0, l1); pl.y = lo2(l2, l3);
            pl.z = lo2(l4, l5); pl.w = lo2(l6, l7);
            *(uint4*)(dsth + i * 8) = ph;
            *(uint4*)(dstl + i * 8) = pl;
        }
    };

    const int lane = tid & 63, wv = tid >> 6;
    const int arow = lane & 15;
    const int brow = wv * 16 + (lane & 15);
    const int kg2 = (lane >> 4) * 8;           // contiguous 8-elem frag offset

    f32x4 acc[4] = {};
    load(0);
    for (int it = 0; it < NIT; ++it) {
        __syncthreads();
        stage();
        __syncthreads();
        if (it + 1 < NIT) load(it + 1);
        #pragma unroll
        for (int c4 = 0; c4 < 2; ++c4) {
            int cb = c4 * 2560 + kg2;
            bf16x8 bh = *(const bf16x8*)&sBh[cb + brow * 40];
            bf16x8 bl = *(const bf16x8*)&sBl[cb + brow * 40];
            #pragma unroll
            for (int mf = 0; mf < 4; ++mf) {
                bf16x8 ah = *(const bf16x8*)&sAh[cb + (arow + mf * 16) * 40];
                bf16x8 al = *(const bf16x8*)&sAl[cb + (arow + mf * 16) * 40];
                acc[mf] = __builtin_amdgcn_mfma_f32_16x16x32_bf16(ah, bh, acc[mf], 0, 0, 0);
                acc[mf] = __builtin_amdgcn_mfma_f32_16x16x32_bf16(ah, bl, acc[mf], 0, 0, 0);
                acc[mf] = __builtin_amdgcn_mfma_f32_16x16x32_bf16(al, bh, acc[mf], 0, 0, 0);
            }
        }
    }
    __syncthreads();

    if (MODE == 0) {
        float* Cf = (float*)shraw;             // [64][68]
        const bool isgc = (n0 < 2048);
        #pragma unroll
        for (int mf = 0; mf < 4; ++mf)
            #pragma unroll
            for (int r = 0; r < 4; ++r) {
                int b = mf * 16 + (lane >> 4) * 4 + r;
                int nl = wv * 16 + (lane & 15);
                float v = acc[mf][r];
                if (isgc) {
                    int n = n0 + nl;
                    v = sigmoidf_(v + b_beta[n]) * context[(size_t)b * 2048 + n];
                }
                Cf[b * 68 + nl] = v;
            }
        __syncthreads();
        int row = tid >> 2, qq = tid & 3;
        float* dst = isgc ? (gc_out + (size_t)row * 2048 + n0)
                          : (P0f + (size_t)row * 2048 + (n0 - 2048));
        #pragma unroll
        for (int j = 0; j < 4; ++j)
            *(float4*)(dst + qq * 16 + j * 4) = *(const float4*)&Cf[row * 68 + qq * 16 + j * 4];
    } else {
        float vals[4][4];
        #pragma unroll
        for (int mf = 0; mf < 4; ++mf)
            #pragma unroll
            for (int r = 0; r < 4; ++r) {
                int b = mf * 16 + (lane >> 4) * 4 + r;
                int G = n0 + wv * 16 + (lane & 15);
                vals[mf][r] = acc[mf][r]
                            + emb_t[(size_t)b * 2048 + G]
                            + P0f[(size_t)b * 2048 + G];
            }
        int basel = lane & ~3;
        #pragma unroll
        for (int mf = 0; mf < 4; ++mf)
            #pragma unroll
            for (int r = 0; r < 4; ++r) {
                float v  = vals[mf][r];
                float vi = __shfl(v, basel);
                float vf = __shfl(v, basel + 1);
                float vg = __shfl(v, basel + 2);
                float vo = __shfl(v, basel + 3);
                if ((lane & 3) == 0) {
                    int b = mf * 16 + (lane >> 4) * 4 + r;
                    int j = (n0 >> 2) + wv * 4 + ((lane & 15) >> 2);
                    size_t ci = (size_t)b * 512 + j;
                    float cn = sigmoidf_(vf) * cbuf[ci] + sigmoidf_(vi) * tanhf(vg);
                    float hn = sigmoidf_(vo) * tanhf(cn);
                    cbuf[ci] = cn;
                    hbuf[ci] = hn;
                    Hbf[((size_t)b * Tt + t) * 512 + j] = bf16r(hn);
                }
            }
    }
}

// ---------------- W_out fp32 -> bf16 ----------------
__global__ __launch_bounds__(256) void k_cvt(const float* __restrict__ src,
                                             ushort_t* __restrict__ dst) {
    int i = blockIdx.x * 256 + threadIdx.x;
    if (i >= (Vv * Hh) / 4) return;
    float4 v = ((const float4*)src)[i];
    ushort4 o;
    o.x = bf16r(v.x); o.y = bf16r(v.y); o.z = bf16r(v.z); o.w = bf16r(v.w);
    ((ushort4*)dst)[i] = o;
}

// ---------------- preds: bf16 MFMA GEMM, 128x128, LDS-staged full-line epilogue -------
__global__ __launch_bounds__(256) void gemm_preds(const ushort_t* __restrict__ Hb,
                                                  const ushort_t* __restrict__ Wb,
                                                  const float* __restrict__ b_out,
                                                  float* __restrict__ preds) {
    const int tid = threadIdx.x;
    const int lane = tid & 63, wave = tid >> 6;
    const int wr = wave >> 1, wc = wave & 1;
    const int m0 = blockIdx.x * 128, n0 = blockIdx.y * 128;

    __shared__ __align__(16) unsigned char shraw2[128 * 132 * 4];
    ushort_t (*As)[40] = (ushort_t(*)[40])shraw2;
    ushort_t (*Bs)[40] = (ushort_t(*)[40])(shraw2 + 128 * 40 * 2);
    float (*Cf)[132] = (float(*)[132])shraw2;

    const int r0 = tid >> 2, c8 = (tid & 3) * 8;
    uint4 pa[2], pb[2];
    auto load = [&](int c) {
        int k0 = c * 32;
        #pragma unroll
        for (int i = 0; i < 2; ++i) {
            int r = r0 + i * 64;
            pa[i] = *(const uint4*)(Hb + (size_t)(m0 + r) * 512 + k0 + c8);
            int gn = n0 + r; gn = (gn > Vv - 1) ? (Vv - 1) : gn;
            pb[i] = *(const uint4*)(Wb + (size_t)gn * 512 + k0 + c8);
        }
    };

    union F8 { bf16x8 v; struct { unsigned long long lo, hi; } u; };
    f32x4 acc[4][4] = {};

    const int arow = wr * 64 + (lane & 15);
    const int brow = wc * 64 + (lane & 15);
    const int kg = (lane >> 4) * 4;

    load(0);
    for (int c = 0; c < 16; ++c) {
        __syncthreads();
        #pragma unroll
        for (int i = 0; i < 2; ++i) {
            *(uint4*)&As[r0 + i * 64][c8] = pa[i];
            *(uint4*)&Bs[r0 + i * 64][c8] = pb[i];
        }
        __syncthreads();
        if (c < 15) load(c + 1);
        F8 af[4], bfr[4];
        #pragma unroll
        for (int x = 0; x < 4; ++x) {
            af[x].u.lo  = *(const unsigned long long*)&As[arow + x * 16][kg];
            af[x].u.hi  = *(const unsigned long long*)&As[arow + x * 16][16 + kg];
            bfr[x].u.lo = *(const unsigned long long*)&Bs[brow + x * 16][kg];
            bfr[x].u.hi = *(const unsigned long long*)&Bs[brow + x * 16][16 + kg];
        }
        #pragma unroll
        for (int mi = 0; mi < 4; ++mi)
            #pragma unroll
            for (int ni = 0; ni < 4; ++ni)
                acc[mi][ni] = __builtin_amdgcn_mfma_f32_16x16x32_bf16(
                    af[mi].v, bfr[ni].v, acc[mi][ni], 0, 0, 0);
    }

    __syncthreads();
    const int crow = (lane >> 4) * 4, ccol = lane & 15;
    #pragma unroll
    for (int mi = 0; mi < 4; ++mi)
        #pragma unroll
        for (int ni = 0; ni < 4; ++ni)
            #pragma unroll
            for (int r = 0; r < 4; ++r)
                Cf[wr * 64 + mi * 16 + crow + r][wc * 64 + ni * 16 + ccol] = acc[mi][ni][r];
    __syncthreads();
    #pragma unroll
    for (int i = 0; i < 16; ++i) {
        int idx = i * 256 + tid;
        int row = idx >> 5, c4 = idx & 31;
        int n = n0 + c4 * 4;
        if (n + 3 < Vv) {
            float4 v = *(const float4*)&Cf[row][c4 * 4];
            float4 bo = *(const float4*)(b_out + n);
            v.x += bo.x; v.y += bo.y; v.z += bo.z; v.w += bo.w;
            *(float4*)(preds + (size_t)(m0 + row) * Vv + n) = v;
        }
    }
}

extern "C" void kernel_launch(void* const* d_in, const int* in_sizes, int n_in,
                              void* d_out, int out_size, void* d_ws, size_t ws_size,
                              hipStream_t stream) {
    const float* img_feat  = (const float*)d_in[0];
    const int*   captions  = (const int*)d_in[1];
    const float* embedding = (const float*)d_in[2];
    const float* W_enc_att = (const float*)d_in[3];
    const float* W_full    = (const float*)d_in[7];
    const float* W_beta    = (const float*)d_in[9];
    const float* b_beta    = (const float*)d_in[10];
    const float* W_ih      = (const float*)d_in[11];
    const float* b_ih      = (const float*)d_in[12];
    const float* W_hh      = (const float*)d_in[13];
    const float* b_hh      = (const float*)d_in[14];
    const float* W_init_h  = (const float*)d_in[15];
    const float* b_init_h  = (const float*)d_in[16];
    const float* W_init_c  = (const float*)d_in[17];
    const float* b_init_c  = (const float*)d_in[18];
    const float* W_out     = (const float*)d_in[19];
    const float* b_out     = (const float*)d_in[20];

    float* preds_out  = (float*)d_out;
    float* alphas_out = (float*)d_out + (size_t)Bsz * Tt * Vv;

    float* ws = (float*)d_ws;
    float* v_enc    = ws;                      // 2048
    float* sc       = v_enc + 2048;            // 12544
    float* alpha    = sc + 12544;              // 12544
    float* context  = alpha + 12544;           // 131072
    float* avg      = context + 131072;        // 131072
    float* hbuf     = avg + 131072;            // 32768  (fp32 h)
    float* cbuf     = hbuf + 32768;            // 32768  (fp32 c)
    float* gc       = cbuf + 32768;            // 131072 (fp32 gc)
    float* P0f      = gc + 131072;             // 131072 (fp32 h@W_hh, perm'd)
    float* emb_part = P0f + 131072;            // 2621440 (fp32, perm'd, biases folded)
    ushort_t* Hbf   = (ushort_t*)(emb_part + 2621440);  // [64][20][512] bf16
    ushort_t* Wout_bf = (ushort_t*)emb_part;   // alias: used only after loop

    // attention (timestep-invariant)
    k_venc<<<32, 256, 0, stream>>>(W_full, W_enc_att, v_enc);
    k_scores<<<dim3(49, 64), 256, 0, stream>>>(img_feat, v_enc, sc);
    k_softmax<<<64, 256, 0, stream>>>(sc, alpha, alphas_out);
    k_ctx<<<dim3(4, 64), 256, 0, stream>>>(img_feat, alpha, context, avg);

    // h0 / c0 init (fp32)
    gemm_init<<<64, 256, 0, stream>>>(
        avg, W_init_h, W_init_c, hbuf, cbuf, b_init_h, b_init_c);

    // embedding part of gates (perm'd cols, b_ih + b_hh folded, fp32 exact)
    gemm_emb<<<dim3(H4 / 64, (Tt * Bsz) / 128), 256, 0, stream>>>(
        captions, embedding, W_ih, emb_part, b_ih, b_hh);

    // recurrence: 2 hi/lo-MFMA dispatches per step
    for (int t = 0; t < Tt; ++t) {
        k_step<0><<<64, 256, 0, stream>>>(
            hbuf, W_beta, W_hh, b_beta, context,
            nullptr, P0f, gc, nullptr, nullptr, nullptr, t);
        k_step<1><<<32, 256, 0, stream>>>(
            gc, W_ih, nullptr, nullptr, nullptr,
            emb_part + (size_t)t * Bsz * H4, P0f, nullptr,
            cbuf, hbuf, Hbf, t);
    }

    // W_out -> bf16 (emb_part dead after loop)
    k_cvt<<<(Vv * Hh / 4 + 255) / 256, 256, 0, stream>>>(W_out, Wout_bf);

    // preds via bf16 MFMA (Hbf rows in b*20+t order, contiguous epilogue writes)
    gemm_preds<<<dim3((Tt * Bsz) / 128, (Vv + 127) / 128), 256, 0, stream>>>(
        Hbf, Wout_bf, b_out, preds_out);
}

// Round 6
// 2181.752 us; speedup vs baseline: 1.1593x; 1.1593x over previous
//
#include <hip/hip_runtime.h>
#include <hip/hip_cooperative_groups.h>
#include <math.h>

namespace cg = cooperative_groups;

#define Bsz 64
#define Pp  196
#define ENC 2048
#define Ee  512
#define Hh  512
#define Vv  10000
#define Tt  20
#define H4  2048

typedef short bf16x8 __attribute__((ext_vector_type(8)));
typedef float f32x4 __attribute__((ext_vector_type(4)));
typedef unsigned short ushort_t;

__device__ __forceinline__ float sigmoidf_(float x) { return 1.0f / (1.0f + expf(-x)); }

__device__ __forceinline__ unsigned short bf16r(float x) {
    union { float f; unsigned int u; } c; c.f = x;
    unsigned int lsb = (c.u >> 16) & 1u;
    return (unsigned short)((c.u + 0x7fffu + lsb) >> 16);
}

// hi = round-half-up bf16 (packed pair), lo = residual
__device__ __forceinline__ unsigned int hi2(float a, float b, float& la, float& lb) {
    unsigned int ua = __float_as_uint(a), ub = __float_as_uint(b);
    unsigned int ha = (ua + 0x8000u) & 0xFFFF0000u;
    unsigned int hb = (ub + 0x8000u) & 0xFFFF0000u;
    la = a - __uint_as_float(ha);
    lb = b - __uint_as_float(hb);
    return (ha >> 16) | hb;
}
__device__ __forceinline__ unsigned int lo2(float la, float lb) {
    unsigned int ua = __float_as_uint(la), ub = __float_as_uint(lb);
    return ((ua + 0x8000u) >> 16) | ((ub + 0x8000u) & 0xFFFF0000u);
}

// split 8 consecutive fp32 -> 8 bf16 hi (uint4) + 8 bf16 lo (uint4)
__device__ __forceinline__ void split8(const float* src, uint4& ph, uint4& pl) {
    float4 a = *(const float4*)src, b = *(const float4*)(src + 4);
    float l0,l1,l2,l3,l4,l5,l6,l7;
    ph.x = hi2(a.x, a.y, l0, l1);
    ph.y = hi2(a.z, a.w, l2, l3);
    ph.z = hi2(b.x, b.y, l4, l5);
    ph.w = hi2(b.z, b.w, l6, l7);
    pl.x = lo2(l0, l1); pl.y = lo2(l2, l3);
    pl.z = lo2(l4, l5); pl.w = lo2(l6, l7);
}

// ---------------- v_enc ----------------
__global__ __launch_bounds__(256) void k_venc(const float* __restrict__ W_full,
                                              const float* __restrict__ W_enc,
                                              float* __restrict__ v_enc) {
    int lane = threadIdx.x & 63, ag = threadIdx.x >> 6;
    int e = blockIdx.x * 64 + lane;
    float s = 0.f;
    #pragma unroll 8
    for (int a = ag * 128; a < ag * 128 + 128; ++a)
        s += W_full[a] * W_enc[(size_t)a * ENC + e];
    __shared__ float red[4][64];
    red[ag][lane] = s;
    __syncthreads();
    if (threadIdx.x < 64)
        v_enc[e] = red[0][lane] + red[1][lane] + red[2][lane] + red[3][lane];
}

// ---------------- scores ----------------
__global__ __launch_bounds__(256) void k_scores(const float* __restrict__ img,
                                                const float* __restrict__ v_enc,
                                                float* __restrict__ sc) {
    int b = blockIdx.y;
    int wave = threadIdx.x >> 6, lane = threadIdx.x & 63;
    int p = blockIdx.x * 4 + wave;
    __shared__ float4 sv[ENC / 4];
    const float4* ve4 = (const float4*)v_enc;
    sv[threadIdx.x] = ve4[threadIdx.x];
    sv[threadIdx.x + 256] = ve4[threadIdx.x + 256];
    __syncthreads();
    const float4* row = (const float4*)(img + ((size_t)b * Pp + p) * ENC);
    float s = 0.f;
    #pragma unroll
    for (int it = 0; it < 8; ++it) {
        int idx = it * 64 + lane;
        float4 v = row[idx];
        float4 w = sv[idx];
        s += v.x * w.x + v.y * w.y + v.z * w.z + v.w * w.w;
    }
    #pragma unroll
    for (int off = 32; off > 0; off >>= 1) s += __shfl_down(s, off);
    if (lane == 0) sc[b * Pp + p] = s;
}

// ---------------- softmax ----------------
__global__ __launch_bounds__(256) void k_softmax(const float* __restrict__ sc,
                                                 float* __restrict__ alpha,
                                                 float* __restrict__ alphas_out) {
    int b = blockIdx.x, tid = threadIdx.x;
    __shared__ float red[256];
    __shared__ float sa[Pp];
    float v = (tid < Pp) ? sc[b * Pp + tid] : -INFINITY;
    red[tid] = v; __syncthreads();
    for (int off = 128; off > 0; off >>= 1) {
        if (tid < off) red[tid] = fmaxf(red[tid], red[tid + off]);
        __syncthreads();
    }
    float mx = red[0]; __syncthreads();
    float ex = (tid < Pp) ? expf(v - mx) : 0.f;
    red[tid] = ex; __syncthreads();
    for (int off = 128; off > 0; off >>= 1) {
        if (tid < off) red[tid] += red[tid + off];
        __syncthreads();
    }
    float inv = 1.f / red[0];
    if (tid < Pp) { sa[tid] = ex * inv; alpha[b * Pp + tid] = ex * inv; }
    __syncthreads();
    for (int i = tid; i < Tt * Pp; i += 256)
        alphas_out[(size_t)b * Tt * Pp + i] = sa[i % Pp];
}

// ---------------- context + avg ----------------
__global__ __launch_bounds__(256) void k_ctx(const float* __restrict__ img,
                                             const float* __restrict__ alpha,
                                             float* __restrict__ context,
                                             float* __restrict__ avg) {
    int b = blockIdx.y;
    int e2 = blockIdx.x * 256 + threadIdx.x;
    __shared__ float sa[Pp];
    if (threadIdx.x < Pp) sa[threadIdx.x] = alpha[b * Pp + threadIdx.x];
    __syncthreads();
    const float2* ib2 = (const float2*)(img + (size_t)b * Pp * ENC);
    float cx = 0.f, cy = 0.f, ax = 0.f, ay = 0.f;
    for (int p = 0; p < Pp; p += 4) {
        #pragma unroll
        for (int q = 0; q < 4; ++q) {
            float ap = sa[p + q];
            float2 v = ib2[(size_t)(p + q) * (ENC / 2) + e2];
            cx += ap * v.x; cy += ap * v.y;
            ax += v.x;      ay += v.y;
        }
    }
    float2* c2 = (float2*)(context + (size_t)b * ENC);
    float2* a2 = (float2*)(avg + (size_t)b * ENC);
    c2[e2] = make_float2(cx, cy);
    a2[e2] = make_float2(ax * (1.f / 196.f), ay * (1.f / 196.f));
}

// ---------------- init GEMM: h0 (hi/lo planes) | c0 = avg @ [Wih|Wic]^T + bias ------
__global__ __launch_bounds__(256) void gemm_init(
    const float* __restrict__ A,
    const float* __restrict__ B0, const float* __restrict__ B1,
    ushort_t* __restrict__ h_hi, ushort_t* __restrict__ h_lo,
    float* __restrict__ cbuf,
    const float* __restrict__ bias0, const float* __restrict__ bias1) {
    const int tid = threadIdx.x;
    const int tx = tid & 15, ty = tid >> 4;
    const int n0 = blockIdx.x * 16;

    const float* Brow = (n0 < 512) ? B0 + (size_t)n0 * ENC : B1 + (size_t)(n0 - 512) * ENC;

    __shared__ float As[64][68];
    __shared__ float Bs[64][20];

    float4 pa[4], pb;
    const int sm[4] = { tid >> 4, (256 + tid) >> 4, (512 + tid) >> 4, (768 + tid) >> 4 };
    const int scc = tid & 15;
    const int bn = tid >> 4, bc = tid & 15;

    auto load_chunk = [&](int c) {
        int k0 = c * 64;
        #pragma unroll
        for (int i = 0; i < 4; ++i)
            pa[i] = *(const float4*)(A + (size_t)sm[i] * ENC + k0 + 4 * scc);
        pb = *(const float4*)(Brow + (size_t)bn * ENC + k0 + 4 * bc);
    };

    float acc[4] = {};
    load_chunk(0);
    for (int c = 0; c < 32; ++c) {
        __syncthreads();
        #pragma unroll
        for (int i = 0; i < 4; ++i) {
            As[4 * scc + 0][sm[i]] = pa[i].x;
            As[4 * scc + 1][sm[i]] = pa[i].y;
            As[4 * scc + 2][sm[i]] = pa[i].z;
            As[4 * scc + 3][sm[i]] = pa[i].w;
        }
        Bs[4 * bc + 0][bn] = pb.x;
        Bs[4 * bc + 1][bn] = pb.y;
        Bs[4 * bc + 2][bn] = pb.z;
        Bs[4 * bc + 3][bn] = pb.w;
        __syncthreads();
        if (c + 1 < 32) load_chunk(c + 1);
        #pragma unroll 8
        for (int kk = 0; kk < 64; ++kk) {
            float4 a = *(const float4*)&As[kk][ty * 4];
            float bb = Bs[kk][tx];
            acc[0] += a.x * bb; acc[1] += a.y * bb;
            acc[2] += a.z * bb; acc[3] += a.w * bb;
        }
    }

    int gn = n0 + tx;
    #pragma unroll
    for (int i = 0; i < 4; ++i) {
        int m = ty * 4 + i;
        if (gn < 512) {
            float v = acc[i] + bias0[gn];
            unsigned int u = __float_as_uint(v);
            unsigned int hb = (u + 0x8000u) & 0xFFFF0000u;
            h_hi[(size_t)m * 512 + gn] = (ushort_t)(hb >> 16);
            h_lo[(size_t)m * 512 + gn] = bf16r(v - __uint_as_float(hb));
        } else {
            cbuf[(size_t)m * 512 + (gn - 512)] = acc[i] + bias1[gn - 512];
        }
    }
}

// ---------------- emb GEMM, fused gather, PERMUTED output columns (G' = j*4+g) ------
__global__ __launch_bounds__(256) void gemm_emb(const int* __restrict__ captions,
                                                const float* __restrict__ emb,
                                                const float* __restrict__ Bm,
                                                float* __restrict__ C,
                                                const float* __restrict__ bias,
                                                const float* __restrict__ bias2) {
    const int tid = threadIdx.x;
    const int tx = tid & 15, ty = tid >> 4;
    const int m0 = blockIdx.y * 128, n0 = blockIdx.x * 64;

    __shared__ float As[32][132];
    __shared__ float Bs[32][68];

    float4 pa[4], pb[2];
    const int am[4] = { tid >> 3, (256 + tid) >> 3, (512 + tid) >> 3, (768 + tid) >> 3 };
    const int ac = tid & 7;
    const int bnr[2] = { tid >> 3, (256 + tid) >> 3 };
    const int bc = tid & 7;

    const float* arow[4];
    #pragma unroll
    for (int i = 0; i < 4; ++i) {
        int r = m0 + am[i];
        arow[i] = emb + (size_t)captions[(r & 63) * Tt + (r >> 6)] * Ee;
    }
    const float* brow[2];
    #pragma unroll
    for (int i = 0; i < 2; ++i) {
        int n = n0 + bnr[i];
        brow[i] = Bm + (size_t)((n & 3) * 512 + (n >> 2)) * 2560;
    }

    const int nchunk = Ee / 32;
    auto load_chunk = [&](int c) {
        int k0 = c * 32;
        #pragma unroll
        for (int i = 0; i < 4; ++i)
            pa[i] = *(const float4*)(arow[i] + k0 + 4 * ac);
        #pragma unroll
        for (int i = 0; i < 2; ++i)
            pb[i] = *(const float4*)(brow[i] + k0 + 4 * bc);
    };

    float acc[8][4] = {};
    load_chunk(0);
    for (int c = 0; c < nchunk; ++c) {
        __syncthreads();
        #pragma unroll
        for (int i = 0; i < 4; ++i) {
            As[4 * ac + 0][am[i]] = pa[i].x;
            As[4 * ac + 1][am[i]] = pa[i].y;
            As[4 * ac + 2][am[i]] = pa[i].z;
            As[4 * ac + 3][am[i]] = pa[i].w;
        }
        #pragma unroll
        for (int i = 0; i < 2; ++i) {
            Bs[4 * bc + 0][bnr[i]] = pb[i].x;
            Bs[4 * bc + 1][bnr[i]] = pb[i].y;
            Bs[4 * bc + 2][bnr[i]] = pb[i].z;
            Bs[4 * bc + 3][bnr[i]] = pb[i].w;
        }
        __syncthreads();
        if (c + 1 < nchunk) load_chunk(c + 1);
        #pragma unroll 4
        for (int kk = 0; kk < 32; ++kk) {
            float4 a0 = *(const float4*)&As[kk][ty * 8];
            float4 a1 = *(const float4*)&As[kk][ty * 8 + 4];
            float4 b0 = *(const float4*)&Bs[kk][tx * 4];
            float av[8] = { a0.x, a0.y, a0.z, a0.w, a1.x, a1.y, a1.z, a1.w };
            float bv[4] = { b0.x, b0.y, b0.z, b0.w };
            #pragma unroll
            for (int i = 0; i < 8; ++i)
                #pragma unroll
                for (int j = 0; j < 4; ++j)
                    acc[i][j] += av[i] * bv[j];
        }
    }

    #pragma unroll
    for (int i = 0; i < 8; ++i) {
        int m = m0 + ty * 8 + i;
        #pragma unroll
        for (int j = 0; j < 4; ++j) {
            int gn = n0 + tx * 4 + j;
            int G = (gn & 3) * 512 + (gn >> 2);
            C[(size_t)m * H4 + gn] = acc[i][j] + bias[G] + bias2[G];
        }
    }
}

// ---------------- persistent cooperative recurrence (weights LDS-resident) -----------
// 256 blocks x 512 thr. Blocks 0-127 = B-role (16 gate cols, K=2048, 128KB LDS + scratch);
// blocks 128-255 = A-role (32 cols of [W_beta|W_hh perm], K=512, 64KB LDS).
// Per step: A-phase (gc hi/lo planes + P0f) -> grid.sync -> B-phase (gates + fused LSTM
// -> h hi/lo planes, cbuf, Hbf) -> grid.sync. hi/lo 3-product MFMA (round-5 numerics).
#define SMEM_BYTES 139776
__global__ __launch_bounds__(512) void k_loop(
    const float* __restrict__ W_beta, const float* __restrict__ b_beta,
    const float* __restrict__ W_ih,   const float* __restrict__ W_hh,
    const float* __restrict__ context, const float* __restrict__ emb_part,
    ushort_t* __restrict__ h_hi, ushort_t* __restrict__ h_lo,
    float* __restrict__ cbuf,
    ushort_t* __restrict__ gc_hi, ushort_t* __restrict__ gc_lo,
    float* __restrict__ P0f, ushort_t* __restrict__ Hbf) {
    cg::grid_group grid = cg::this_grid();
    extern __shared__ __align__(16) unsigned char smem[];
    ushort_t* Whi = (ushort_t*)smem;

    const int tid = threadIdx.x, bid = blockIdx.x;
    const bool isB = (bid < 128);
    const int lane = tid & 63, w = tid >> 6;

    // ---- one-time weight preload into LDS (bf16 hi/lo, swizzled slots) ----
    if (isB) {
        ushort_t* Wlo = Whi + 32768;
        const int G0 = bid * 16;
        #pragma unroll
        for (int p = 0; p < 8; ++p) {
            int s = p * 512 + tid;
            int r = s >> 8, ks = s & 255;
            int kc = ks >> 2, sl = ks & 3;
            int Gp = G0 + r;
            const float* src = W_ih + (size_t)((Gp & 3) * 512 + (Gp >> 2)) * 2560 + 512
                             + kc * 32 + sl * 8;
            uint4 ph, pl; split8(src, ph, pl);
            int off = (kc * 16 + r) * 32 + ((sl ^ ((r >> 1) & 3)) << 3);
            *(uint4*)&Whi[off] = ph;
            *(uint4*)&Wlo[off] = pl;
        }
    } else {
        ushort_t* Wlo = Whi + 16384;
        const int nA0 = (bid - 128) * 32;
        #pragma unroll
        for (int p = 0; p < 4; ++p) {
            int s = p * 512 + tid;
            int r = s >> 6, ks = s & 63;
            int kc = ks >> 2, sl = ks & 3;
            int n = nA0 + r;
            const float* src;
            if (n < 2048) src = W_beta + (size_t)n * 512;
            else { int g = n - 2048; src = W_hh + (size_t)((g & 3) * 512 + (g >> 2)) * 512; }
            src += kc * 32 + sl * 8;
            uint4 ph, pl; split8(src, ph, pl);
            int off = (kc * 32 + r) * 32 + ((sl ^ ((r >> 1) & 3)) << 3);
            *(uint4*)&Whi[off] = ph;
            *(uint4*)&Wlo[off] = pl;
        }
    }
    __syncthreads();

    const int sl = lane >> 4;

    for (int t = 0; t < Tt; ++t) {
        if (!isB) {
            // ---- phase A: preact = h @ [W_beta | W_hh]^T ----
            const int nA0 = (bid - 128) * 32;
            const int mf = w >> 1, nf = w & 1;
            const int brow = mf * 16 + (lane & 15);
            const int rloc = nf * 16 + (lane & 15);
            const ushort_t* Wlo = Whi + 16384;
            const int woff0 = rloc * 32 + ((sl ^ ((rloc >> 1) & 3)) << 3);
            const ushort_t* hh = h_hi + (size_t)brow * 512 + sl * 8;
            const ushort_t* hl = h_lo + (size_t)brow * 512 + sl * 8;
            f32x4 acc = {};
            #pragma unroll 4
            for (int kc = 0; kc < 16; ++kc) {
                bf16x8 ah = *(const bf16x8*)(hh + kc * 32);
                bf16x8 al = *(const bf16x8*)(hl + kc * 32);
                int off = kc * 1024 + woff0;
                bf16x8 wh = *(const bf16x8*)&Whi[off];
                bf16x8 wl = *(const bf16x8*)&Wlo[off];
                acc = __builtin_amdgcn_mfma_f32_16x16x32_bf16(al, wh, acc, 0, 0, 0);
                acc = __builtin_amdgcn_mfma_f32_16x16x32_bf16(ah, wl, acc, 0, 0, 0);
                acc = __builtin_amdgcn_mfma_f32_16x16x32_bf16(ah, wh, acc, 0, 0, 0);
            }
            int n = nA0 + rloc;
            if (n < 2048) {
                float bb = b_beta[n];
                #pragma unroll
                for (int r = 0; r < 4; ++r) {
                    int b = mf * 16 + (lane >> 4) * 4 + r;
                    float v = sigmoidf_(acc[r] + bb) * context[(size_t)b * 2048 + n];
                    unsigned int u = __float_as_uint(v);
                    unsigned int hb = (u + 0x8000u) & 0xFFFF0000u;
                    gc_hi[(size_t)b * 2048 + n] = (ushort_t)(hb >> 16);
                    gc_lo[(size_t)b * 2048 + n] = bf16r(v - __uint_as_float(hb));
                }
            } else {
                #pragma unroll
                for (int r = 0; r < 4; ++r) {
                    int b = mf * 16 + (lane >> 4) * 4 + r;
                    P0f[(size_t)b * 2048 + (n - 2048)] = acc[r];
                }
            }
        }
        grid.sync();
        if (isB) {
            // ---- phase B: gates = gc @ W_ih[:,512:]^T (+P0+emb) + fused LSTM ----
            const int G0 = bid * 16;
            const int mw = w & 3, kh = w >> 2;
            const int brow = mw * 16 + (lane & 15);
            const int rloc = lane & 15;
            const ushort_t* Wlo = Whi + 32768;
            float* gsum = (float*)(smem + 131072);   // [2][64][17]
            const int woff0 = rloc * 32 + ((sl ^ ((rloc >> 1) & 3)) << 3);
            const ushort_t* gh = gc_hi + (size_t)brow * 2048 + sl * 8;
            const ushort_t* gl = gc_lo + (size_t)brow * 2048 + sl * 8;
            f32x4 acc = {};
            #pragma unroll 4
            for (int kc2 = 0; kc2 < 32; ++kc2) {
                int kc = kh * 32 + kc2;
                bf16x8 ah = *(const bf16x8*)(gh + kc * 32);
                bf16x8 al = *(const bf16x8*)(gl + kc * 32);
                int off = kc * 512 + woff0;
                bf16x8 wh = *(const bf16x8*)&Whi[off];
                bf16x8 wl = *(const bf16x8*)&Wlo[off];
                acc = __builtin_amdgcn_mfma_f32_16x16x32_bf16(al, wh, acc, 0, 0, 0);
                acc = __builtin_amdgcn_mfma_f32_16x16x32_bf16(ah, wl, acc, 0, 0, 0);
                acc = __builtin_amdgcn_mfma_f32_16x16x32_bf16(ah, wh, acc, 0, 0, 0);
            }
            #pragma unroll
            for (int r = 0; r < 4; ++r) {
                int b = mw * 16 + (lane >> 4) * 4 + r;
                gsum[(kh * 64 + b) * 17 + rloc] = acc[r];
            }
            __syncthreads();
            if (tid < 256) {
                int b = tid >> 2, jl = tid & 3;
                const float* ep = emb_part + (size_t)t * Bsz * H4 + (size_t)b * 2048 + G0;
                const float* pp = P0f + (size_t)b * 2048 + G0;
                float g4[4];
                #pragma unroll
                for (int g = 0; g < 4; ++g) {
                    int nl = jl * 4 + g;
                    g4[g] = gsum[b * 17 + nl] + gsum[(64 + b) * 17 + nl]
                          + pp[nl] + ep[nl];
                }
                int j = bid * 4 + jl;
                size_t ci = (size_t)b * 512 + j;
                float cn = sigmoidf_(g4[1]) * cbuf[ci] + sigmoidf_(g4[0]) * tanhf(g4[2]);
                float hn = sigmoidf_(g4[3]) * tanhf(cn);
                cbuf[ci] = cn;
                unsigned int u = __float_as_uint(hn);
                unsigned int hb = (u + 0x8000u) & 0xFFFF0000u;
                h_hi[ci] = (ushort_t)(hb >> 16);
                h_lo[ci] = bf16r(hn - __uint_as_float(hb));
                Hbf[((size_t)b * Tt + t) * 512 + j] = bf16r(hn);
            }
        }
        grid.sync();
    }
}

// ---------------- W_out fp32 -> bf16 ----------------
__global__ __launch_bounds__(256) void k_cvt(const float* __restrict__ src,
                                             ushort_t* __restrict__ dst) {
    int i = blockIdx.x * 256 + threadIdx.x;
    if (i >= (Vv * Hh) / 4) return;
    float4 v = ((const float4*)src)[i];
    ushort4 o;
    o.x = bf16r(v.x); o.y = bf16r(v.y); o.z = bf16r(v.z); o.w = bf16r(v.w);
    ((ushort4*)dst)[i] = o;
}

// ---------------- preds: bf16 MFMA GEMM, 128x128, LDS-staged full-line epilogue ------
__global__ __launch_bounds__(256) void gemm_preds(const ushort_t* __restrict__ Hb,
                                                  const ushort_t* __restrict__ Wb,
                                                  const float* __restrict__ b_out,
                                                  float* __restrict__ preds) {
    const int tid = threadIdx.x;
    const int lane = tid & 63, wave = tid >> 6;
    const int wr = wave >> 1, wc = wave & 1;
    const int m0 = blockIdx.x * 128, n0 = blockIdx.y * 128;

    __shared__ __align__(16) unsigned char shraw2[128 * 132 * 4];
    ushort_t (*As)[40] = (ushort_t(*)[40])shraw2;
    ushort_t (*Bs)[40] = (ushort_t(*)[40])(shraw2 + 128 * 40 * 2);
    float (*Cf)[132] = (float(*)[132])shraw2;

    const int r0 = tid >> 2, c8 = (tid & 3) * 8;
    uint4 pa[2], pb[2];
    auto load = [&](int c) {
        int k0 = c * 32;
        #pragma unroll
        for (int i = 0; i < 2; ++i) {
            int r = r0 + i * 64;
            pa[i] = *(const uint4*)(Hb + (size_t)(m0 + r) * 512 + k0 + c8);
            int gn = n0 + r; gn = (gn > Vv - 1) ? (Vv - 1) : gn;
            pb[i] = *(const uint4*)(Wb + (size_t)gn * 512 + k0 + c8);
        }
    };

    union F8 { bf16x8 v; struct { unsigned long long lo, hi; } u; };
    f32x4 acc[4][4] = {};

    const int arow = wr * 64 + (lane & 15);
    const int brow = wc * 64 + (lane & 15);
    const int kg = (lane >> 4) * 4;

    load(0);
    for (int c = 0; c < 16; ++c) {
        __syncthreads();
        #pragma unroll
        for (int i = 0; i < 2; ++i) {
            *(uint4*)&As[r0 + i * 64][c8] = pa[i];
            *(uint4*)&Bs[r0 + i * 64][c8] = pb[i];
        }
        __syncthreads();
        if (c < 15) load(c + 1);
        F8 af[4], bfr[4];
        #pragma unroll
        for (int x = 0; x < 4; ++x) {
            af[x].u.lo  = *(const unsigned long long*)&As[arow + x * 16][kg];
            af[x].u.hi  = *(const unsigned long long*)&As[arow + x * 16][16 + kg];
            bfr[x].u.lo = *(const unsigned long long*)&Bs[brow + x * 16][kg];
            bfr[x].u.hi = *(const unsigned long long*)&Bs[brow + x * 16][16 + kg];
        }
        #pragma unroll
        for (int mi = 0; mi < 4; ++mi)
            #pragma unroll
            for (int ni = 0; ni < 4; ++ni)
                acc[mi][ni] = __builtin_amdgcn_mfma_f32_16x16x32_bf16(
                    af[mi].v, bfr[ni].v, acc[mi][ni], 0, 0, 0);
    }

    __syncthreads();
    const int crow = (lane >> 4) * 4, ccol = lane & 15;
    #pragma unroll
    for (int mi = 0; mi < 4; ++mi)
        #pragma unroll
        for (int ni = 0; ni < 4; ++ni)
            #pragma unroll
            for (int r = 0; r < 4; ++r)
                Cf[wr * 64 + mi * 16 + crow + r][wc * 64 + ni * 16 + ccol] = acc[mi][ni][r];
    __syncthreads();
    #pragma unroll
    for (int i = 0; i < 16; ++i) {
        int idx = i * 256 + tid;
        int row = idx >> 5, c4 = idx & 31;
        int n = n0 + c4 * 4;
        if (n + 3 < Vv) {
            float4 v = *(const float4*)&Cf[row][c4 * 4];
            float4 bo = *(const float4*)(b_out + n);
            v.x += bo.x; v.y += bo.y; v.z += bo.z; v.w += bo.w;
            *(float4*)(preds + (size_t)(m0 + row) * Vv + n) = v;
        }
    }
}

extern "C" void kernel_launch(void* const* d_in, const int* in_sizes, int n_in,
                              void* d_out, int out_size, void* d_ws, size_t ws_size,
                              hipStream_t stream) {
    const float* img_feat  = (const float*)d_in[0];
    const int*   captions  = (const int*)d_in[1];
    const float* embedding = (const float*)d_in[2];
    const float* W_enc_att = (const float*)d_in[3];
    const float* W_full    = (const float*)d_in[7];
    const float* W_beta    = (const float*)d_in[9];
    const float* b_beta    = (const float*)d_in[10];
    const float* W_ih      = (const float*)d_in[11];
    const float* b_ih      = (const float*)d_in[12];
    const float* W_hh      = (const float*)d_in[13];
    const float* b_hh      = (const float*)d_in[14];
    const float* W_init_h  = (const float*)d_in[15];
    const float* b_init_h  = (const float*)d_in[16];
    const float* W_init_c  = (const float*)d_in[17];
    const float* b_init_c  = (const float*)d_in[18];
    const float* W_out     = (const float*)d_in[19];
    const float* b_out     = (const float*)d_in[20];

    float* preds_out  = (float*)d_out;
    float* alphas_out = (float*)d_out + (size_t)Bsz * Tt * Vv;

    float* ws = (float*)d_ws;
    float* v_enc    = ws;                      // 2048
    float* sc       = v_enc + 2048;            // 12544
    float* alpha    = sc + 12544;              // 12544
    float* context  = alpha + 12544;           // 131072
    float* avg      = context + 131072;        // 131072
    float* cbuf     = avg + 131072;            // 32768
    float* P0f      = cbuf + 32768;            // 131072
    float* emb_part = P0f + 131072;            // 2621440
    float* planes   = emb_part + 2621440;
    ushort_t* h_hi  = (ushort_t*)planes;                 // 64*512
    ushort_t* h_lo  = h_hi + Bsz * Hh;                   // 64*512
    ushort_t* gc_hi = h_lo + Bsz * Hh;                   // 64*2048
    ushort_t* gc_lo = gc_hi + Bsz * ENC;                 // 64*2048
    ushort_t* Hbf   = gc_lo + Bsz * ENC;                 // 64*20*512
    ushort_t* Wout_bf = (ushort_t*)emb_part;   // alias: used only after loop

    // attention (timestep-invariant)
    k_venc<<<32, 256, 0, stream>>>(W_full, W_enc_att, v_enc);
    k_scores<<<dim3(49, 64), 256, 0, stream>>>(img_feat, v_enc, sc);
    k_softmax<<<64, 256, 0, stream>>>(sc, alpha, alphas_out);
    k_ctx<<<dim3(4, 64), 256, 0, stream>>>(img_feat, alpha, context, avg);

    // h0 (hi/lo planes) / c0
    gemm_init<<<64, 256, 0, stream>>>(
        avg, W_init_h, W_init_c, h_hi, h_lo, cbuf, b_init_h, b_init_c);

    // embedding part of gates (perm'd cols, biases folded, fp32 exact)
    gemm_emb<<<dim3(H4 / 64, (Tt * Bsz) / 128), 256, 0, stream>>>(
        captions, embedding, W_ih, emb_part, b_ih, b_hh);

    // persistent cooperative recurrence (weights LDS-resident, 1 launch for 20 steps)
    hipFuncSetAttribute((const void*)k_loop,
                        hipFuncAttributeMaxDynamicSharedMemorySize, SMEM_BYTES);
    {
        const float* a0 = W_beta;  const float* a1 = b_beta;
        const float* a2 = W_ih;    const float* a3 = W_hh;
        const float* a4 = context; const float* a5 = emb_part;
        ushort_t* a6 = h_hi; ushort_t* a7 = h_lo;
        float* a8 = cbuf;
        ushort_t* a9 = gc_hi; ushort_t* a10 = gc_lo;
        float* a11 = P0f; ushort_t* a12 = Hbf;
        void* args[] = { &a0, &a1, &a2, &a3, &a4, &a5, &a6, &a7, &a8, &a9,
                         &a10, &a11, &a12 };
        hipLaunchCooperativeKernel((const void*)k_loop, dim3(256), dim3(512),
                                   args, SMEM_BYTES, stream);
    }

    // W_out -> bf16 (emb_part dead after loop)
    k_cvt<<<(Vv * Hh / 4 + 255) / 256, 256, 0, stream>>>(W_out, Wout_bf);

    // preds via bf16 MFMA (Hbf rows in b*20+t order, contiguous epilogue writes)
    gemm_preds<<<dim3((Tt * Bsz) / 128, (Vv + 127) / 128), 256, 0, stream>>>(
        Hbf, Wout_bf, b_out, preds_out);
}